// Round 1
// baseline (742.164 us; speedup 1.0000x reference)
//
#include <hip/hip_runtime.h>
#include <math.h>

// Problem constants (from setup_inputs): B,V,C,D,H,W = 2,5,32,48,128,160
constexpr int B_ = 2;
constexpr int V_ = 5;
constexpr int C_ = 32;
constexpr int D_ = 48;
constexpr int H_ = 128;
constexpr int W_ = 160;
constexpr int HW_ = H_ * W_;               // 20480
constexpr int NVOX = B_ * D_ * HW_;        // 1,966,080
constexpr int PLANE = D_ * HW_;            // 983,040 (per-batch voxels)

// ---------------- small matrix helpers (device) ----------------

__device__ inline void combine4(const float* pm, float out[4][4]) {
    // pm -> (2,4,4): E = pm[0..15], K = pm[16..31]
    const float* E = pm;
    const float* K = pm + 16;
    for (int i = 0; i < 3; ++i)
        for (int j = 0; j < 4; ++j) {
            float a = 0.f;
            for (int k = 0; k < 3; ++k) a += K[i * 4 + k] * E[k * 4 + j];
            out[i][j] = a;
        }
    for (int j = 0; j < 4; ++j) out[3][j] = E[12 + j];
}

__device__ inline void invert4(const float A[4][4], float inv[4][4]) {
    float M[4][8];
    for (int i = 0; i < 4; ++i)
        for (int j = 0; j < 4; ++j) {
            M[i][j] = A[i][j];
            M[i][4 + j] = (i == j) ? 1.f : 0.f;
        }
    for (int col = 0; col < 4; ++col) {
        int piv = col;
        float best = fabsf(M[col][col]);
        for (int r = col + 1; r < 4; ++r) {
            float v = fabsf(M[r][col]);
            if (v > best) { best = v; piv = r; }
        }
        if (piv != col)
            for (int j = 0; j < 8; ++j) { float t = M[col][j]; M[col][j] = M[piv][j]; M[piv][j] = t; }
        float ip = 1.f / M[col][col];
        for (int j = 0; j < 8; ++j) M[col][j] *= ip;
        for (int r = 0; r < 4; ++r) {
            if (r == col) continue;
            float f = M[r][col];
            for (int j = 0; j < 8; ++j) M[r][j] -= f * M[col][j];
        }
    }
    for (int i = 0; i < 4; ++i)
        for (int j = 0; j < 4; ++j) inv[i][j] = M[i][4 + j];
}

// setup: per b: ref_proj, inv(ref_proj); per src view v: P = src_proj @ inv_ref
// store rot(9)+trans(3) = 12 floats at rt[(b*(V-1)+v-1)*12]
__global__ void setup_kernel(const float* __restrict__ proj, float* __restrict__ rt) {
    int b = threadIdx.x;
    if (b >= B_) return;
    float ref[4][4], inv[4][4];
    combine4(proj + (size_t)((b * V_ + 0) * 2) * 16, ref);
    invert4(ref, inv);
    for (int v = 1; v < V_; ++v) {
        float src[4][4];
        combine4(proj + (size_t)((b * V_ + v) * 2) * 16, src);
        float P[3][4];
        for (int i = 0; i < 3; ++i)
            for (int j = 0; j < 4; ++j) {
                float a = 0.f;
                for (int k = 0; k < 4; ++k) a += src[i][k] * inv[k][j];
                P[i][j] = a;
            }
        float* o = rt + (size_t)(b * (V_ - 1) + (v - 1)) * 12;
        o[0] = P[0][0]; o[1] = P[0][1]; o[2] = P[0][2];
        o[3] = P[1][0]; o[4] = P[1][1]; o[5] = P[1][2];
        o[6] = P[2][0]; o[7] = P[2][1]; o[8] = P[2][2];
        o[9] = P[0][3]; o[10] = P[1][3]; o[11] = P[2][3];
    }
}

// transpose features (B,V,C,H,W) -> channel-last (B,V,H,W,C)
__global__ __launch_bounds__(256) void transpose_kernel(const float* __restrict__ feat,
                                                        float* __restrict__ feat_cl) {
    int idx = blockIdx.x * 256 + threadIdx.x;  // over B*V*HW
    if (idx >= B_ * V_ * HW_) return;
    int pix = idx % HW_;
    int bv = idx / HW_;
    const float* src = feat + (size_t)bv * C_ * HW_ + pix;
    float f[C_];
#pragma unroll
    for (int c = 0; c < C_; ++c) f[c] = src[(size_t)c * HW_];
    float4* dst = (float4*)(feat_cl + (size_t)idx * C_);
#pragma unroll
    for (int i = 0; i < 8; ++i)
        dst[i] = make_float4(f[4 * i], f[4 * i + 1], f[4 * i + 2], f[4 * i + 3]);
}

// fused homography warp + bilinear + variance + conv-channel-reduction (T planes)
// T layout: [j=0..26][b][d][h][w]
__global__ __launch_bounds__(256) void warp_kernel(const float* __restrict__ feat_cl,
                                                   const float* __restrict__ rt,
                                                   const float* __restrict__ dv,
                                                   const float* __restrict__ wreg,
                                                   float* __restrict__ T) {
    __shared__ float lds_wt[27 * 32];          // wt[j][c] from wreg[c*27+j]
    __shared__ float lds_rt[B_ * (V_ - 1) * 12];
    __shared__ float lds_dv[B_ * D_];
    int tid = threadIdx.x;
    for (int t = tid; t < 27 * 32; t += 256) {
        int j = t >> 5, c = t & 31;
        lds_wt[t] = wreg[c * 27 + j];
    }
    for (int t = tid; t < B_ * (V_ - 1) * 12; t += 256) lds_rt[t] = rt[t];
    for (int t = tid; t < B_ * D_; t += 256) lds_dv[t] = dv[t];
    __syncthreads();

    int vox = blockIdx.x * 256 + tid;
    if (vox >= NVOX) return;
    int w = vox % W_;
    int h = (vox / W_) % H_;
    int d = (vox / HW_) % D_;
    int b = vox / PLANE;
    float wf = (float)w, hf = (float)h;
    float dep = lds_dv[b * D_ + d];

    float4 s[8], q[8];
    {
        const float4* rp = (const float4*)(feat_cl + ((size_t)(b * V_) * HW_ + (size_t)(h * W_ + w)) * C_);
#pragma unroll
        for (int i = 0; i < 8; ++i) {
            float4 r = rp[i];
            s[i] = r;
            q[i] = make_float4(r.x * r.x, r.y * r.y, r.z * r.z, r.w * r.w);
        }
    }

#pragma unroll
    for (int v = 1; v < V_; ++v) {
        const float* m = &lds_rt[(b * (V_ - 1) + v - 1) * 12];
        float xp = fmaf(fmaf(m[0], wf, fmaf(m[1], hf, m[2])), dep, m[9]);
        float yp = fmaf(fmaf(m[3], wf, fmaf(m[4], hf, m[5])), dep, m[10]);
        float zp = fmaf(fmaf(m[6], wf, fmaf(m[7], hf, m[8])), dep, m[11]);
        float iz = 1.0f / zp;
        float ix = xp * iz, iy = yp * iz;
        float x0f = floorf(ix), y0f = floorf(iy);
        float wx1 = ix - x0f, wx0 = 1.f - wx1;
        float wy1 = iy - y0f, wy0 = 1.f - wy1;
        float x1f = x0f + 1.f, y1f = y0f + 1.f;
        bool vx0 = (x0f >= 0.f) && (x0f <= (float)(W_ - 1));
        bool vx1 = (x1f >= 0.f) && (x1f <= (float)(W_ - 1));
        bool vy0 = (y0f >= 0.f) && (y0f <= (float)(H_ - 1));
        bool vy1 = (y1f >= 0.f) && (y1f <= (float)(H_ - 1));
        int x0i = (int)fminf(fmaxf(x0f, 0.f), (float)(W_ - 1));
        int x1i = (int)fminf(fmaxf(x1f, 0.f), (float)(W_ - 1));
        int y0i = (int)fminf(fmaxf(y0f, 0.f), (float)(H_ - 1));
        int y1i = (int)fminf(fmaxf(y1f, 0.f), (float)(H_ - 1));
        float w00 = wx0 * wy0 * ((vx0 && vy0) ? 1.f : 0.f);
        float w01 = wx1 * wy0 * ((vx1 && vy0) ? 1.f : 0.f);
        float w10 = wx0 * wy1 * ((vx0 && vy1) ? 1.f : 0.f);
        float w11 = wx1 * wy1 * ((vx1 && vy1) ? 1.f : 0.f);
        const float* base = feat_cl + (size_t)(b * V_ + v) * HW_ * C_;
        const float4* p00 = (const float4*)(base + (size_t)(y0i * W_ + x0i) * C_);
        const float4* p01 = (const float4*)(base + (size_t)(y0i * W_ + x1i) * C_);
        const float4* p10 = (const float4*)(base + (size_t)(y1i * W_ + x0i) * C_);
        const float4* p11 = (const float4*)(base + (size_t)(y1i * W_ + x1i) * C_);
#pragma unroll
        for (int i = 0; i < 8; ++i) {
            float4 a = p00[i], bb = p01[i], cg = p10[i], dg = p11[i];
            float4 acc;
            acc.x = fmaf(a.x, w00, fmaf(bb.x, w01, fmaf(cg.x, w10, dg.x * w11)));
            acc.y = fmaf(a.y, w00, fmaf(bb.y, w01, fmaf(cg.y, w10, dg.y * w11)));
            acc.z = fmaf(a.z, w00, fmaf(bb.z, w01, fmaf(cg.z, w10, dg.z * w11)));
            acc.w = fmaf(a.w, w00, fmaf(bb.w, w01, fmaf(cg.w, w10, dg.w * w11)));
            s[i].x += acc.x; s[i].y += acc.y; s[i].z += acc.z; s[i].w += acc.w;
            q[i].x = fmaf(acc.x, acc.x, q[i].x);
            q[i].y = fmaf(acc.y, acc.y, q[i].y);
            q[i].z = fmaf(acc.z, acc.z, q[i].z);
            q[i].w = fmaf(acc.w, acc.w, q[i].w);
        }
    }

    // variance into s[]
    const float invV = 1.0f / (float)V_;
#pragma unroll
    for (int i = 0; i < 8; ++i) {
        float mx = s[i].x * invV, my = s[i].y * invV, mz = s[i].z * invV, mw = s[i].w * invV;
        s[i].x = fmaf(-mx, mx, q[i].x * invV);
        s[i].y = fmaf(-my, my, q[i].y * invV);
        s[i].z = fmaf(-mz, mz, q[i].z * invV);
        s[i].w = fmaf(-mw, mw, q[i].w * invV);
    }

    // T_j = sum_c var[c] * wt[j][c]
#pragma unroll
    for (int j = 0; j < 27; ++j) {
        const float4* wt = (const float4*)&lds_wt[j * 32];
        float a = 0.f;
#pragma unroll
        for (int i = 0; i < 8; ++i) {
            float4 wv = wt[i];
            a = fmaf(s[i].x, wv.x, a);
            a = fmaf(s[i].y, wv.y, a);
            a = fmaf(s[i].z, wv.z, a);
            a = fmaf(s[i].w, wv.w, a);
        }
        T[(size_t)j * NVOX + vox] = a;
    }
}

// cost[p] = sum_j T_j[p + off_j], SAME zero padding (per-batch d,h,w bounds)
__global__ __launch_bounds__(256) void cost_kernel(const float* __restrict__ T,
                                                   float* __restrict__ cost) {
    int vox = blockIdx.x * 256 + threadIdx.x;
    if (vox >= NVOX) return;
    int w = vox % W_;
    int h = (vox / W_) % H_;
    int d = (vox / HW_) % D_;
    float acc = 0.f;
#pragma unroll
    for (int kd = 0; kd < 3; ++kd) {
        int dd = d + kd - 1;
        if (dd < 0 || dd >= D_) continue;
#pragma unroll
        for (int kh = 0; kh < 3; ++kh) {
            int hh = h + kh - 1;
            if (hh < 0 || hh >= H_) continue;
#pragma unroll
            for (int kw = 0; kw < 3; ++kw) {
                int ww = w + kw - 1;
                if (ww < 0 || ww >= W_) continue;
                int j = kd * 9 + kh * 3 + kw;
                acc += T[(size_t)j * NVOX + vox + (kd - 1) * HW_ + (kh - 1) * W_ + (kw - 1)];
            }
        }
    }
    cost[vox] = acc;
}

// softmax over D + depth + conf + itg
__global__ __launch_bounds__(256) void out_kernel(const float* __restrict__ cost,
                                                  const float* __restrict__ dv,
                                                  float* __restrict__ out) {
    int tid = blockIdx.x * 256 + threadIdx.x;  // over B*HW
    if (tid >= B_ * HW_) return;
    int pix = tid % HW_;
    int b = tid / HW_;
    const float* cb = cost + (size_t)b * PLANE + pix;
    float p[D_];
    float mx = -1e30f;
#pragma unroll
    for (int d = 0; d < D_; ++d) {
        p[d] = cb[(size_t)d * HW_];
        mx = fmaxf(mx, p[d]);
    }
    float S = 0.f;
#pragma unroll
    for (int d = 0; d < D_; ++d) {
        p[d] = expf(p[d] - mx);
        S += p[d];
    }
    float invS = 1.f / S;
    float S2 = 0.f;
#pragma unroll
    for (int d = 0; d < D_; ++d) {
        p[d] *= invS;            // prob
        S2 += p[d];
    }
    float invS2 = 1.f / fmaxf(S2, 1e-12f);
    float depth = 0.f, dif = 0.f;
#pragma unroll
    for (int d = 0; d < D_; ++d) {
        depth = fmaf(p[d] * invS2, dv[b * D_ + d], depth);
        dif = fmaf(p[d], (float)d, dif);
    }
    int di = (int)dif;           // truncation toward zero (dif >= 0)
    di = min(max(di, 0), D_ - 1);
    float conf = 0.f;
#pragma unroll
    for (int k = -1; k <= 2; ++k) {
        int idx = di + k;
        if (idx >= 0 && idx < D_) conf += p[idx];
    }
    out[tid] = depth;
    out[B_ * HW_ + tid] = conf;
    float* itg = out + 2 * B_ * HW_ + (size_t)b * PLANE + pix;
#pragma unroll
    for (int d = 0; d < D_; ++d) itg[(size_t)d * HW_] = p[d] * invS2;
}

extern "C" void kernel_launch(void* const* d_in, const int* in_sizes, int n_in,
                              void* d_out, int out_size, void* d_ws, size_t ws_size,
                              hipStream_t stream) {
    const float* feat = (const float*)d_in[0];   // (B,V,C,H,W)
    const float* proj = (const float*)d_in[1];   // (B,V,2,4,4)
    const float* dv   = (const float*)d_in[2];   // (B,D)
    const float* wreg = (const float*)d_in[3];   // (1,C,3,3,3)
    float* out = (float*)d_out;
    float* ws = (float*)d_ws;

    // workspace layout (floats)
    const size_t rt_off = 0;
    const size_t rt_sz = 128;
    const size_t fcl_off = rt_off + rt_sz;
    const size_t fcl_sz = (size_t)B_ * V_ * HW_ * C_;     // 6,553,600
    const size_t T_off = fcl_off + fcl_sz;
    const size_t T_sz = (size_t)27 * NVOX;                // 53,084,160
    const size_t cost_off = T_off + T_sz;
    const size_t cost_sz = (size_t)NVOX;                  // 1,966,080
    const size_t need = (cost_off + cost_sz) * sizeof(float);
    if (ws_size < need) return;  // workspace too small — fail loudly (out stays poisoned)

    float* rt = ws + rt_off;
    float* feat_cl = ws + fcl_off;
    float* T = ws + T_off;
    float* cost = ws + cost_off;

    setup_kernel<<<1, 64, 0, stream>>>(proj, rt);
    transpose_kernel<<<(B_ * V_ * HW_) / 256, 256, 0, stream>>>(feat, feat_cl);
    warp_kernel<<<NVOX / 256, 256, 0, stream>>>(feat_cl, rt, dv, wreg, T);
    cost_kernel<<<NVOX / 256, 256, 0, stream>>>(T, cost);
    out_kernel<<<(B_ * HW_) / 256, 256, 0, stream>>>(cost, dv, out);
}

// Round 2
// 367.161 us; speedup vs baseline: 2.0214x; 2.0214x over previous
//
#include <hip/hip_runtime.h>
#include <math.h>

// Problem constants (from setup_inputs): B,V,C,D,H,W = 2,5,32,48,128,160
constexpr int B_ = 2;
constexpr int V_ = 5;
constexpr int C_ = 32;
constexpr int D_ = 48;
constexpr int H_ = 128;
constexpr int W_ = 160;
constexpr int HW_ = H_ * W_;               // 20480
constexpr int NVOX = B_ * D_ * HW_;        // 1,966,080
constexpr int PLANE = D_ * HW_;            // 983,040 (per-batch voxels)

static_assert((NVOX * 4) % 256 == 0, "warp grid must divide evenly");

// ---------------- small matrix helpers (device) ----------------

__device__ inline void combine4(const float* pm, float out[4][4]) {
    const float* E = pm;
    const float* K = pm + 16;
    for (int i = 0; i < 3; ++i)
        for (int j = 0; j < 4; ++j) {
            float a = 0.f;
            for (int k = 0; k < 3; ++k) a += K[i * 4 + k] * E[k * 4 + j];
            out[i][j] = a;
        }
    for (int j = 0; j < 4; ++j) out[3][j] = E[12 + j];
}

__device__ inline void invert4(const float A[4][4], float inv[4][4]) {
    float M[4][8];
    for (int i = 0; i < 4; ++i)
        for (int j = 0; j < 4; ++j) {
            M[i][j] = A[i][j];
            M[i][4 + j] = (i == j) ? 1.f : 0.f;
        }
    for (int col = 0; col < 4; ++col) {
        int piv = col;
        float best = fabsf(M[col][col]);
        for (int r = col + 1; r < 4; ++r) {
            float v = fabsf(M[r][col]);
            if (v > best) { best = v; piv = r; }
        }
        if (piv != col)
            for (int j = 0; j < 8; ++j) { float t = M[col][j]; M[col][j] = M[piv][j]; M[piv][j] = t; }
        float ip = 1.f / M[col][col];
        for (int j = 0; j < 8; ++j) M[col][j] *= ip;
        for (int r = 0; r < 4; ++r) {
            if (r == col) continue;
            float f = M[r][col];
            for (int j = 0; j < 8; ++j) M[r][j] -= f * M[col][j];
        }
    }
    for (int i = 0; i < 4; ++i)
        for (int j = 0; j < 4; ++j) inv[i][j] = M[i][4 + j];
}

__global__ void setup_kernel(const float* __restrict__ proj, float* __restrict__ rt) {
    int b = threadIdx.x;
    if (b >= B_) return;
    float ref[4][4], inv[4][4];
    combine4(proj + (size_t)((b * V_ + 0) * 2) * 16, ref);
    invert4(ref, inv);
    for (int v = 1; v < V_; ++v) {
        float src[4][4];
        combine4(proj + (size_t)((b * V_ + v) * 2) * 16, src);
        float P[3][4];
        for (int i = 0; i < 3; ++i)
            for (int j = 0; j < 4; ++j) {
                float a = 0.f;
                for (int k = 0; k < 4; ++k) a += src[i][k] * inv[k][j];
                P[i][j] = a;
            }
        float* o = rt + (size_t)(b * (V_ - 1) + (v - 1)) * 12;
        o[0] = P[0][0]; o[1] = P[0][1]; o[2] = P[0][2];
        o[3] = P[1][0]; o[4] = P[1][1]; o[5] = P[1][2];
        o[6] = P[2][0]; o[7] = P[2][1]; o[8] = P[2][2];
        o[9] = P[0][3]; o[10] = P[1][3]; o[11] = P[2][3];
    }
}

// transpose features (B,V,C,H,W) -> channel-last (B,V,H,W,C)
__global__ __launch_bounds__(256) void transpose_kernel(const float* __restrict__ feat,
                                                        float* __restrict__ feat_cl) {
    int idx = blockIdx.x * 256 + threadIdx.x;  // over B*V*HW
    if (idx >= B_ * V_ * HW_) return;
    int pix = idx % HW_;
    int bv = idx / HW_;
    const float* src = feat + (size_t)bv * C_ * HW_ + pix;
    float f[C_];
#pragma unroll
    for (int c = 0; c < C_; ++c) f[c] = src[(size_t)c * HW_];
    float4* dst = (float4*)(feat_cl + (size_t)idx * C_);
#pragma unroll
    for (int i = 0; i < 8; ++i)
        dst[i] = make_float4(f[4 * i], f[4 * i + 1], f[4 * i + 2], f[4 * i + 3]);
}

// Fused homography warp + bilinear + variance + conv-channel-reduction.
// C-split: 4 threads per voxel (8 channels each) -> 4x waves, small register
// footprint, deep load pipelining. T layout: [j=0..26][b][d][h][w].
__global__ __launch_bounds__(256) void warp_kernel(const float* __restrict__ feat_cl,
                                                   const float* __restrict__ rt,
                                                   const float* __restrict__ dv,
                                                   const float* __restrict__ wreg,
                                                   float* __restrict__ T) {
    __shared__ float lds_wt[27 * 32];          // wt[j][c] from wreg[c*27+j]
    __shared__ float lds_rt[B_ * (V_ - 1) * 12];
    __shared__ float lds_dv[B_ * D_];
    int tid = threadIdx.x;
    for (int t = tid; t < 27 * 32; t += 256) {
        int j = t >> 5, c = t & 31;
        lds_wt[t] = wreg[c * 27 + j];
    }
    for (int t = tid; t < B_ * (V_ - 1) * 12; t += 256) lds_rt[t] = rt[t];
    for (int t = tid; t < B_ * D_; t += 256) lds_dv[t] = dv[t];
    __syncthreads();

    int g = blockIdx.x * 256 + tid;            // over NVOX*4
    int vox = g >> 2;
    int cq = g & 3;                            // channel quarter (8 ch)
    int coff = cq * 8;
    int w = vox % W_;
    int h = (vox / W_) % H_;
    int d = (vox / HW_) % D_;
    int b = vox / PLANE;
    float wf = (float)w, hf = (float)h;
    float dep = lds_dv[b * D_ + d];

    float4 s0, s1, q0, q1;
    {
        const float4* rp = (const float4*)(feat_cl +
            ((size_t)(b * V_) * HW_ + (size_t)(h * W_ + w)) * C_ + coff);
        s0 = rp[0];
        s1 = rp[1];
        q0 = make_float4(s0.x * s0.x, s0.y * s0.y, s0.z * s0.z, s0.w * s0.w);
        q1 = make_float4(s1.x * s1.x, s1.y * s1.y, s1.z * s1.z, s1.w * s1.w);
    }

#pragma unroll
    for (int v = 1; v < V_; ++v) {
        const float* m = &lds_rt[(b * (V_ - 1) + v - 1) * 12];
        float xp = fmaf(fmaf(m[0], wf, fmaf(m[1], hf, m[2])), dep, m[9]);
        float yp = fmaf(fmaf(m[3], wf, fmaf(m[4], hf, m[5])), dep, m[10]);
        float zp = fmaf(fmaf(m[6], wf, fmaf(m[7], hf, m[8])), dep, m[11]);
        float iz = 1.0f / zp;
        float ix = xp * iz, iy = yp * iz;
        float x0f = floorf(ix), y0f = floorf(iy);
        float wx1 = ix - x0f, wx0 = 1.f - wx1;
        float wy1 = iy - y0f, wy0 = 1.f - wy1;
        float x1f = x0f + 1.f, y1f = y0f + 1.f;
        bool vx0 = (x0f >= 0.f) && (x0f <= (float)(W_ - 1));
        bool vx1 = (x1f >= 0.f) && (x1f <= (float)(W_ - 1));
        bool vy0 = (y0f >= 0.f) && (y0f <= (float)(H_ - 1));
        bool vy1 = (y1f >= 0.f) && (y1f <= (float)(H_ - 1));
        int x0i = (int)fminf(fmaxf(x0f, 0.f), (float)(W_ - 1));
        int x1i = (int)fminf(fmaxf(x1f, 0.f), (float)(W_ - 1));
        int y0i = (int)fminf(fmaxf(y0f, 0.f), (float)(H_ - 1));
        int y1i = (int)fminf(fmaxf(y1f, 0.f), (float)(H_ - 1));
        float w00 = wx0 * wy0 * ((vx0 && vy0) ? 1.f : 0.f);
        float w01 = wx1 * wy0 * ((vx1 && vy0) ? 1.f : 0.f);
        float w10 = wx0 * wy1 * ((vx0 && vy1) ? 1.f : 0.f);
        float w11 = wx1 * wy1 * ((vx1 && vy1) ? 1.f : 0.f);
        const float* base = feat_cl + (size_t)(b * V_ + v) * HW_ * C_ + coff;
        const float4* p00 = (const float4*)(base + (size_t)(y0i * W_ + x0i) * C_);
        const float4* p01 = (const float4*)(base + (size_t)(y0i * W_ + x1i) * C_);
        const float4* p10 = (const float4*)(base + (size_t)(y1i * W_ + x0i) * C_);
        const float4* p11 = (const float4*)(base + (size_t)(y1i * W_ + x1i) * C_);
        float4 a0 = p00[0], a1 = p00[1];
        float4 b0 = p01[0], b1 = p01[1];
        float4 c0 = p10[0], c1 = p10[1];
        float4 d0 = p11[0], d1 = p11[1];
        float4 acc0, acc1;
        acc0.x = fmaf(a0.x, w00, fmaf(b0.x, w01, fmaf(c0.x, w10, d0.x * w11)));
        acc0.y = fmaf(a0.y, w00, fmaf(b0.y, w01, fmaf(c0.y, w10, d0.y * w11)));
        acc0.z = fmaf(a0.z, w00, fmaf(b0.z, w01, fmaf(c0.z, w10, d0.z * w11)));
        acc0.w = fmaf(a0.w, w00, fmaf(b0.w, w01, fmaf(c0.w, w10, d0.w * w11)));
        acc1.x = fmaf(a1.x, w00, fmaf(b1.x, w01, fmaf(c1.x, w10, d1.x * w11)));
        acc1.y = fmaf(a1.y, w00, fmaf(b1.y, w01, fmaf(c1.y, w10, d1.y * w11)));
        acc1.z = fmaf(a1.z, w00, fmaf(b1.z, w01, fmaf(c1.z, w10, d1.z * w11)));
        acc1.w = fmaf(a1.w, w00, fmaf(b1.w, w01, fmaf(c1.w, w10, d1.w * w11)));
        s0.x += acc0.x; s0.y += acc0.y; s0.z += acc0.z; s0.w += acc0.w;
        s1.x += acc1.x; s1.y += acc1.y; s1.z += acc1.z; s1.w += acc1.w;
        q0.x = fmaf(acc0.x, acc0.x, q0.x); q0.y = fmaf(acc0.y, acc0.y, q0.y);
        q0.z = fmaf(acc0.z, acc0.z, q0.z); q0.w = fmaf(acc0.w, acc0.w, q0.w);
        q1.x = fmaf(acc1.x, acc1.x, q1.x); q1.y = fmaf(acc1.y, acc1.y, q1.y);
        q1.z = fmaf(acc1.z, acc1.z, q1.z); q1.w = fmaf(acc1.w, acc1.w, q1.w);
    }

    // variance for this thread's 8 channels
    const float invV = 1.0f / (float)V_;
    float4 var0, var1;
    {
        float mx = s0.x * invV, my = s0.y * invV, mz = s0.z * invV, mw = s0.w * invV;
        var0.x = fmaf(-mx, mx, q0.x * invV);
        var0.y = fmaf(-my, my, q0.y * invV);
        var0.z = fmaf(-mz, mz, q0.z * invV);
        var0.w = fmaf(-mw, mw, q0.w * invV);
        mx = s1.x * invV; my = s1.y * invV; mz = s1.z * invV; mw = s1.w * invV;
        var1.x = fmaf(-mx, mx, q1.x * invV);
        var1.y = fmaf(-my, my, q1.y * invV);
        var1.z = fmaf(-mz, mz, q1.z * invV);
        var1.w = fmaf(-mw, mw, q1.w * invV);
    }

    // T_j = sum_c var[c]*wt[j][c]; partial dot over 8 channels, then 4-lane
    // butterfly (lanes 4k..4k+3 share a voxel). Lane cq writes taps j%4==cq.
#pragma unroll
    for (int j = 0; j < 27; ++j) {
        const float4* wt = (const float4*)&lds_wt[j * 32 + coff];
        float4 w0 = wt[0], w1 = wt[1];
        float a = var0.x * w0.x;
        a = fmaf(var0.y, w0.y, a);
        a = fmaf(var0.z, w0.z, a);
        a = fmaf(var0.w, w0.w, a);
        a = fmaf(var1.x, w1.x, a);
        a = fmaf(var1.y, w1.y, a);
        a = fmaf(var1.z, w1.z, a);
        a = fmaf(var1.w, w1.w, a);
        a += __shfl_xor(a, 1);
        a += __shfl_xor(a, 2);
        if ((j & 3) == cq) T[(size_t)j * NVOX + vox] = a;
    }
}

// cost[p] = sum_j T_j[p + off_j], SAME zero padding (per-batch d,h,w bounds)
__global__ __launch_bounds__(256) void cost_kernel(const float* __restrict__ T,
                                                   float* __restrict__ cost) {
    int vox = blockIdx.x * 256 + threadIdx.x;
    if (vox >= NVOX) return;
    int w = vox % W_;
    int h = (vox / W_) % H_;
    int d = (vox / HW_) % D_;
    float acc = 0.f;
#pragma unroll
    for (int kd = 0; kd < 3; ++kd) {
        int dd = d + kd - 1;
        if (dd < 0 || dd >= D_) continue;
#pragma unroll
        for (int kh = 0; kh < 3; ++kh) {
            int hh = h + kh - 1;
            if (hh < 0 || hh >= H_) continue;
#pragma unroll
            for (int kw = 0; kw < 3; ++kw) {
                int ww = w + kw - 1;
                if (ww < 0 || ww >= W_) continue;
                int j = kd * 9 + kh * 3 + kw;
                acc += T[(size_t)j * NVOX + vox + (kd - 1) * HW_ + (kh - 1) * W_ + (kw - 1)];
            }
        }
    }
    cost[vox] = acc;
}

// softmax over D + depth + conf + itg
__global__ __launch_bounds__(256) void out_kernel(const float* __restrict__ cost,
                                                  const float* __restrict__ dv,
                                                  float* __restrict__ out) {
    int tid = blockIdx.x * 256 + threadIdx.x;  // over B*HW
    if (tid >= B_ * HW_) return;
    int pix = tid % HW_;
    int b = tid / HW_;
    const float* cb = cost + (size_t)b * PLANE + pix;
    float p[D_];
    float mx = -1e30f;
#pragma unroll
    for (int d = 0; d < D_; ++d) {
        p[d] = cb[(size_t)d * HW_];
        mx = fmaxf(mx, p[d]);
    }
    float S = 0.f;
#pragma unroll
    for (int d = 0; d < D_; ++d) {
        p[d] = expf(p[d] - mx);
        S += p[d];
    }
    float invS = 1.f / S;
    float S2 = 0.f;
#pragma unroll
    for (int d = 0; d < D_; ++d) {
        p[d] *= invS;            // prob
        S2 += p[d];
    }
    float invS2 = 1.f / fmaxf(S2, 1e-12f);
    float depth = 0.f, dif = 0.f;
#pragma unroll
    for (int d = 0; d < D_; ++d) {
        depth = fmaf(p[d] * invS2, dv[b * D_ + d], depth);
        dif = fmaf(p[d], (float)d, dif);
    }
    int di = (int)dif;
    di = min(max(di, 0), D_ - 1);
    float conf = 0.f;
#pragma unroll
    for (int k = -1; k <= 2; ++k) {
        int idx = di + k;
        if (idx >= 0 && idx < D_) conf += p[idx];
    }
    out[tid] = depth;
    out[B_ * HW_ + tid] = conf;
    float* itg = out + 2 * B_ * HW_ + (size_t)b * PLANE + pix;
#pragma unroll
    for (int d = 0; d < D_; ++d) itg[(size_t)d * HW_] = p[d] * invS2;
}

extern "C" void kernel_launch(void* const* d_in, const int* in_sizes, int n_in,
                              void* d_out, int out_size, void* d_ws, size_t ws_size,
                              hipStream_t stream) {
    const float* feat = (const float*)d_in[0];   // (B,V,C,H,W)
    const float* proj = (const float*)d_in[1];   // (B,V,2,4,4)
    const float* dv   = (const float*)d_in[2];   // (B,D)
    const float* wreg = (const float*)d_in[3];   // (1,C,3,3,3)
    float* out = (float*)d_out;
    float* ws = (float*)d_ws;

    // workspace layout (floats)
    const size_t rt_off = 0;
    const size_t rt_sz = 128;
    const size_t fcl_off = rt_off + rt_sz;
    const size_t fcl_sz = (size_t)B_ * V_ * HW_ * C_;     // 6,553,600
    const size_t T_off = fcl_off + fcl_sz;
    const size_t T_sz = (size_t)27 * NVOX;                // 53,084,160
    const size_t cost_off = T_off + T_sz;
    const size_t cost_sz = (size_t)NVOX;                  // 1,966,080
    const size_t need = (cost_off + cost_sz) * sizeof(float);
    if (ws_size < need) return;  // workspace too small — fail loudly

    float* rt = ws + rt_off;
    float* feat_cl = ws + fcl_off;
    float* T = ws + T_off;
    float* cost = ws + cost_off;

    setup_kernel<<<1, 64, 0, stream>>>(proj, rt);
    transpose_kernel<<<(B_ * V_ * HW_) / 256, 256, 0, stream>>>(feat, feat_cl);
    warp_kernel<<<(NVOX * 4) / 256, 256, 0, stream>>>(feat_cl, rt, dv, wreg, T);
    cost_kernel<<<NVOX / 256, 256, 0, stream>>>(T, cost);
    out_kernel<<<(B_ * HW_) / 256, 256, 0, stream>>>(cost, dv, out);
}